// Round 8
// baseline (2590.482 us; speedup 1.0000x reference)
//
#include <hip/hip_runtime.h>
#include <hip/hip_bf16.h>

#define N_PTS 8192
#define LATENT 64

typedef __attribute__((ext_vector_type(8))) short short8;
typedef __attribute__((ext_vector_type(4))) float f32x4;

#define MFMA16(a, b, c) __builtin_amdgcn_mfma_f32_16x16x32_bf16(a, b, c, 0, 0, 0)

__device__ __forceinline__ unsigned short f2bf_rne(float f) {
    unsigned u = __float_as_uint(f);
    u += 0x7fff + ((u >> 16) & 1);
    return (unsigned short)(u >> 16);
}
__device__ __forceinline__ float bf2f(unsigned short h) {
    return __uint_as_float(((unsigned)h) << 16);
}
// pack high-16 of two fp32 bit patterns: low half <- lo>>16, high half <- hi>>16
__device__ __forceinline__ unsigned pack_hi16(unsigned lo, unsigned hi) {
    return __builtin_amdgcn_perm(hi, lo, 0x07060302);
}
// after this add, the high 16 bits are the RNE bf16 of the input pattern
__device__ __forceinline__ unsigned rne_hi(unsigned u) {
    return u + 0x7fff + ((u >> 16) & 1);
}

// k-dimension permutation (kappa): activation for output-index o of the
// previous layer is stored at k-position kappa(o). Baked into A-plane writes
// (epilogues) and B-plane k-order (combine kernels).
__device__ __forceinline__ int kappa(int o) {
    int j  = (((o >> 3) & 1) << 2) | ((o >> 4) & 3);
    int qk = (o >> 1) & 3;
    int kc = ((o >> 6) << 1) | (o & 1);
    return (kc << 5) | (qk << 3) | j;
}

// ---------------------------------------------------------------------------
// Kernel 1: gate GEMV + top-k -> compact (idx, val) AND inverted per-expert
// subscriber lists (n, gate) for the combine pass.
// ---------------------------------------------------------------------------
struct GateParams {
    const float* latents;
    const float* gw[5];
    const float* gb[5];
    int*   idx_out;   // [5][64][256]
    float* val_out;   // [5][64][256]
    int*   cnt;       // [5][1024]
    int2*  inv;       // [5][1024][64]  (n, float bits of gate)
    int E[5];
    int K[5];
};

__global__ __launch_bounds__(256) void gate_topk(GateParams P) {
    const int n = blockIdx.x, l = blockIdx.y, t = threadIdx.x;
    const int E = P.E[l], K = P.K[l];
    __shared__ float lat[LATENT];
    __shared__ float gv[1024];
    __shared__ float ga[1024];
    __shared__ int s_cntgt, s_pos;

    if (t < LATENT) lat[t] = P.latents[(n * 5 + l) * LATENT + t];
    if (t == 0) { s_cntgt = 0; s_pos = 0; }
    __syncthreads();

    const float* gwl = P.gw[l];
    const float* gbl = P.gb[l];
    for (int e = t; e < E; e += 256) {
        float acc = gbl[e];
        const float* row = gwl + e * LATENT;
        #pragma unroll 8
        for (int j = 0; j < LATENT; ++j) acc = fmaf(lat[j], row[j], acc);
        gv[e] = acc;
        ga[e] = fabsf(acc);
    }

    for (int size = 2; size <= E; size <<= 1) {
        for (int stride = size >> 1; stride > 0; stride >>= 1) {
            __syncthreads();
            for (int i = t; i < E; i += 256) {
                int j = i ^ stride;
                if (j > i) {
                    float a = ga[i], b = ga[j];
                    bool up = ((i & size) == 0);
                    if ((a > b) == up) { ga[i] = b; ga[j] = a; }
                }
            }
        }
    }
    __syncthreads();
    const float thr = ga[E - K];

    for (int e = t; e < E; e += 256)
        if (fabsf(gv[e]) > thr) atomicAdd(&s_cntgt, 1);
    __syncthreads();
    const int needed = K - s_cntgt;

    for (int e = t; e < E; e += 256) {
        float a = fabsf(gv[e]);
        bool keep = (a > thr);
        if (!keep && a == thr) {
            int r = 0;
            for (int e2 = 0; e2 < e; ++e2)
                if (fabsf(gv[e2]) == thr) ++r;
            keep = (r < needed);
        }
        if (keep) {
            int pos = atomicAdd(&s_pos, 1);
            P.idx_out[(l * 64 + n) * 256 + pos] = e;
            P.val_out[(l * 64 + n) * 256 + pos] = gv[e];
            int slot = atomicAdd(&P.cnt[l * 1024 + e], 1);
            P.inv[(l * 1024 + e) * 64 + slot] = make_int2(n, __float_as_int(gv[e]));
        }
    }
}

// ---------------------------------------------------------------------------
// Kernel 2: combines.
//  b [0,64)    : layer-0 W fragment bank (compact lists)
//  b [64,832)  : layers 1-3 INVERTED combine, one block per (layer, o).
//                Each expert row read ONCE; acc[n][k] in LDS, thread owns
//                column k exclusively -> no barriers, no conflicts.
//  b [832,835) : layer-4 inverted, one block per output o (E=1024)
//  b [835,899) : bias combines per n (compact lists)
// ---------------------------------------------------------------------------
struct CombParams {
    const float *w0, *b0, *w1, *b1, *w2, *b2, *w3, *b3, *w4, *b4;
    const int* idxl; const float* vall;
    const int* cnt; const int2* inv;
    unsigned short* W0F;
    unsigned short *Bh1, *Bl1, *Bh2, *Bl2, *Bh3, *Bl3, *Bh4, *Bl4;
    float *bc1, *bc2, *bc3, *bc4;
};

__global__ __launch_bounds__(256) void combine_all(CombParams C) {
    const int b = blockIdx.x;
    const int t = threadIdx.x;
    __shared__ float acc[16384];          // 64 KB; aliased by W0F section
    int*   sidx = (int*)acc;
    float* sval = acc + 256;

    if (b < 64) {
        // ---- layer-0 fragment bank: rows [wxh,wyh,bh,wxl,wyl,bl,wxh,wyh] ----
        const int n = b;
        if (t < 4) { sidx[t] = C.idxl[n * 256 + t]; sval[t] = C.vall[n * 256 + t]; }
        __syncthreads();
        const int o = t;
        float wx = 0.f, wy = 0.f, bb = 0.f;
        #pragma unroll
        for (int e = 0; e < 4; ++e) {
            const float g = sval[e];
            const float2 ww = ((const float2*)C.w0)[sidx[e] * 256 + o];
            wx = fmaf(g, ww.x, wx);
            wy = fmaf(g, ww.y, wy);
            bb = fmaf(g, C.b0[sidx[e] * 256 + o], bb);
        }
        unsigned short wxh = f2bf_rne(wx), wyh = f2bf_rne(wy), bh = f2bf_rne(bb);
        unsigned short wxl = f2bf_rne(wx - bf2f(wxh));
        unsigned short wyl = f2bf_rne(wy - bf2f(wyh));
        unsigned short bl  = f2bf_rne(bb - bf2f(bh));
        const int wv = o >> 6, ntl = (o >> 4) & 3, colo = o & 15;
        short8 frag = { (short)wxh, (short)wyh, (short)bh, (short)wxl,
                        (short)wyl, (short)bl,  (short)wxh, (short)wyh };
        short8 zero = { 0, 0, 0, 0, 0, 0, 0, 0 };
        short8* dst = (short8*)C.W0F + n * 1024 + wv * 256 + ntl * 64 + colo;
        dst[0]  = frag;   // quad 0 holds the live k-slots
        dst[16] = zero;   // quads 1..3 zero
        dst[32] = zero;
        dst[48] = zero;
    } else if (b < 835) {
        // ---- inverted combine (layers 1-3: per (l,o); layer 4: per o) ----
        int l, o, E; const float* wrow; long estride;
        unsigned short *Bh, *Bl;
        if (b < 832) {
            l = 1 + ((b - 64) >> 8);
            o = (b - 64) & 255;
            E = (l == 1) ? 16 : (l == 2) ? 64 : 256;
            const float* w = (l == 1) ? C.w1 : (l == 2) ? C.w2 : C.w3;
            wrow = w + (long)o * 256 + t;        // w[(e*256+o)*256 + t]
            estride = 65536;
            Bh = (l == 1) ? C.Bh1 : (l == 2) ? C.Bh2 : C.Bh3;
            Bl = (l == 1) ? C.Bl1 : (l == 2) ? C.Bl2 : C.Bl3;
        } else {
            l = 4;
            o = b - 832;
            E = 1024;
            wrow = C.w4 + (long)o * 256 + t;     // w4[(e*3+o)*256 + t]
            estride = 768;
            Bh = C.Bh4; Bl = C.Bl4;
        }
        // zero own column (no sync needed: thread t owns acc[n*256+t] for all n)
        for (int n = 0; n < 64; ++n) acc[n * 256 + t] = 0.f;

        const int*  cnt = C.cnt + l * 1024;
        const int2* inv = C.inv + l * 1024 * 64;

        float wb[8];
        #pragma unroll
        for (int p = 0; p < 8; ++p) wb[p] = wrow[(long)p * estride];
        for (int e = 0; e < E; e += 8) {
            #pragma unroll
            for (int u = 0; u < 8; ++u) {
                const int ee = e + u;
                const float wv = wb[u];
                if (ee + 8 < E) wb[u] = wrow[(long)(ee + 8) * estride];
                const int c = cnt[ee];
                for (int s = 0; s < c; ++s) {
                    const int2 iv = inv[ee * 64 + s];
                    const float g = __int_as_float(iv.y);
                    acc[iv.x * 256 + t] = fmaf(g, wv, acc[iv.x * 256 + t]);
                }
            }
        }
        // store with kappa layout (same formulas as original combine)
        const int kap = kappa(t);
        const int kc = kap >> 5, qk = (kap >> 3) & 3, j = kap & 7;
        if (l < 4) {
            const int nt = o >> 4, colo = o & 15;
            const int flat = (((kc * 16 + nt) << 6) + (qk << 4) + colo) * 8 + j;
            for (int n = 0; n < 64; ++n) {
                const float a = acc[n * 256 + t];
                const unsigned short h = f2bf_rne(a);
                Bh[(size_t)n * 65536 + flat] = h;
                Bl[(size_t)n * 65536 + flat] = f2bf_rne(a - bf2f(h));
            }
        } else {
            const int flat = ((kc << 6) + (qk << 4) + o) * 8 + j;
            for (int n = 0; n < 64; ++n) {
                const float a = acc[n * 256 + t];
                const unsigned short h = f2bf_rne(a);
                Bh[(size_t)n * 4096 + flat] = h;
                Bl[(size_t)n * 4096 + flat] = f2bf_rne(a - bf2f(h));
            }
        }
    } else {
        // ---- bias combines for n = b-835 (compact lists) ----
        const int n = b - 835;
        float s1 = 0.f, s2 = 0.f, s3 = 0.f;
        #pragma unroll
        for (int e = 0; e < 4; ++e) {
            const int   i1 = C.idxl[(1 * 64 + n) * 256 + e];
            const float g1 = C.vall[(1 * 64 + n) * 256 + e];
            s1 = fmaf(g1, C.b1[i1 * 256 + t], s1);
        }
        for (int e = 0; e < 32; ++e) {
            const int   i2 = C.idxl[(2 * 64 + n) * 256 + e];
            const float g2 = C.vall[(2 * 64 + n) * 256 + e];
            s2 = fmaf(g2, C.b2[i2 * 256 + t], s2);
            const int   i3 = C.idxl[(3 * 64 + n) * 256 + e];
            const float g3 = C.vall[(3 * 64 + n) * 256 + e];
            s3 = fmaf(g3, C.b3[i3 * 256 + t], s3);
        }
        C.bc1[n * 256 + t] = s1;
        C.bc2[n * 256 + t] = s2;
        C.bc3[n * 256 + t] = s3;
        if (t < 3) {
            float s = 0.f;
            for (int e = 0; e < 256; ++e) {
                const int   i4 = C.idxl[(4 * 64 + n) * 256 + e];
                const float g4 = C.vall[(4 * 64 + n) * 256 + e];
                s = fmaf(g4, C.b4[i4 * 3 + t], s);
            }
            C.bc4[n * 3 + t] = s;
        }
    }
}

// ---------------------------------------------------------------------------
// Kernel 3: fused 5-layer MLP — EXACT round-4 structure (verified 526 us,
// MfmaUtil 60%, VGPR 64, zero spill). Do not touch.
// ---------------------------------------------------------------------------
struct FusedParams {
    const float* coords;
    const unsigned short* W0F;
    const unsigned short *Bh1, *Bl1; const float* bc1;
    const unsigned short *Bh2, *Bl2; const float* bc2;
    const unsigned short *Bh3, *Bl3; const float* bc3;
    const unsigned short *Bh4, *Bl4; const float* bc4;
    float* out;
};

__device__ __forceinline__ void epilogue_store8(
        unsigned short (*PL)[16384], const f32x4 (*acc)[4], const float* bo30,
        int w, int lane) {
    const int quad = lane >> 4, col = lane & 15;
    const int qk  = (col >> 1) & 3;
    const int kcW = ((w >> 1) << 1) | (col & 1);
    const int jb  = ((col >> 3) << 2) | ((w & 1) << 1);
    const int gb  = kcW * 2048 + qk * 128 + quad * 32 + jb;
    unsigned short* wp0 = &PL[0][gb];
    unsigned short* wp1 = &PL[1][gb];
    #pragma unroll
    for (int mt = 0; mt < 4; ++mt) {
        #pragma unroll
        for (int r = 0; r < 4; ++r) {
            unsigned u[2], v[2];
            #pragma unroll
            for (int ntl = 0; ntl < 2; ++ntl) {
                float x = __sinf(fmaf(acc[ntl][mt][r], 30.f, bo30[ntl]));
                unsigned ux = __float_as_uint(x);
                u[ntl] = ux;
                float rres = x - __uint_as_float(ux & 0xffff0000u);
                v[ntl] = rne_hi(__float_as_uint(rres));
            }
            const unsigned hp = pack_hi16(u[0], u[1]);
            const unsigned lp = pack_hi16(v[0], v[1]);
            const int offs = mt * 512 + ((r ^ qk) << 3);
            *(unsigned*)(wp0 + offs) = hp;
            *(unsigned*)(wp1 + offs) = lp;
        }
    }
}

__device__ __forceinline__ void hidden_layer8(
        unsigned short (*PL)[16384],
        const short8* __restrict__ Bh, const short8* __restrict__ Bl,
        const float* __restrict__ bc, int w, int lane, int lanep) {
    const int col = lane & 15;
    f32x4 acc[2][4];
    #pragma unroll
    for (int a = 0; a < 2; ++a)
        #pragma unroll
        for (int m = 0; m < 4; ++m) acc[a][m] = (f32x4){0.f, 0.f, 0.f, 0.f};

    const short8* a0 = (const short8*)&PL[0][lanep * 8];
    const short8* a1 = (const short8*)&PL[1][lanep * 8];
    const short8* bph = Bh + (w << 7) + lane;
    const short8* bpl = Bl + (w << 7) + lane;

    short8 pbh[2][2], pbl[2][2];
    #pragma unroll
    for (int ntl = 0; ntl < 2; ++ntl) {
        pbh[0][ntl] = bph[ntl << 6];
        pbl[0][ntl] = bpl[ntl << 6];
    }
    #pragma unroll
    for (int kc = 0; kc < 8; ++kc) {
        const int cur = kc & 1;
        if (kc < 7) {
            #pragma unroll
            for (int ntl = 0; ntl < 2; ++ntl) {
                pbh[cur ^ 1][ntl] = bph[(kc + 1) * 1024 + (ntl << 6)];
                pbl[cur ^ 1][ntl] = bpl[(kc + 1) * 1024 + (ntl << 6)];
            }
        }
        short8 Ah[4], Al[4];
        #pragma unroll
        for (int mt = 0; mt < 4; ++mt) {
            Ah[mt] = a0[(kc * 4 + mt) << 6];
            Al[mt] = a1[(kc * 4 + mt) << 6];
        }
        #pragma unroll
        for (int ntl = 0; ntl < 2; ++ntl) {
            #pragma unroll
            for (int mt = 0; mt < 4; ++mt) {
                acc[ntl][mt] = MFMA16(Ah[mt], pbh[cur][ntl], acc[ntl][mt]);
                acc[ntl][mt] = MFMA16(Ah[mt], pbl[cur][ntl], acc[ntl][mt]);
                acc[ntl][mt] = MFMA16(Al[mt], pbh[cur][ntl], acc[ntl][mt]);
            }
        }
    }
    __syncthreads();   // all A reads done before in-place overwrite

    float bo30[2];
    #pragma unroll
    for (int ntl = 0; ntl < 2; ++ntl)
        bo30[ntl] = 30.f * bc[(w << 5) + (ntl << 4) + col];
    epilogue_store8(PL, acc, bo30, w, lane);
    __syncthreads();
}

__global__ __launch_bounds__(512, 4) void fused_mlp(FusedParams P) {
    __shared__ __align__(16) unsigned short PL[2][16384];   // Ah, Al planes (64 KB)
    const int bid = blockIdx.x;
    const int n = bid >> 7;
    const int p0g = (bid & 127) * 64;
    const int t = threadIdx.x;
    const int lane = t & 63, w = t >> 6;      // w in [0,8)
    const int quad = lane >> 4, col = lane & 15;
    const int lanep = lane ^ ((lane >> 4) & 3);

    // ---- layer 0 via MFMA: A = [cxh,cyh,1,cxh,cyh,1,cxl,cyl] in quad-0 ----
    {
        short8 A0[4];
        if (quad == 0) {
            #pragma unroll
            for (int mt = 0; mt < 4; ++mt) {
                const float2 c = ((const float2*)P.coords)[n * N_PTS + p0g + mt * 16 + col];
                unsigned ux = __float_as_uint(c.x), uy = __float_as_uint(c.y);
                unsigned xh = ux & 0xffff0000u, yh = uy & 0xffff0000u;
                unsigned short xl = f2bf_rne(c.x - __uint_as_float(xh));
                unsigned short yl = f2bf_rne(c.y - __uint_as_float(yh));
                short8 a = { (short)(xh >> 16), (short)(yh >> 16), (short)0x3f80,
                             (short)(xh >> 16), (short)(yh >> 16), (short)0x3f80,
                             (short)xl, (short)yl };
                A0[mt] = a;
            }
        } else {
            short8 z = { 0, 0, 0, 0, 0, 0, 0, 0 };
            #pragma unroll
            for (int mt = 0; mt < 4; ++mt) A0[mt] = z;
        }
        f32x4 acc[2][4];
        const short8* b0p = (const short8*)P.W0F + n * 1024 + (w >> 1) * 256
                          + ((w & 1) << 7) + lane;
        #pragma unroll
        for (int ntl = 0; ntl < 2; ++ntl) {
            const short8 b0 = b0p[ntl << 6];
            #pragma unroll
            for (int mt = 0; mt < 4; ++mt) {
                f32x4 z = (f32x4){0.f, 0.f, 0.f, 0.f};
                acc[ntl][mt] = MFMA16(A0[mt], b0, z);
            }
        }
        const float bz[2] = { 0.f, 0.f };
        epilogue_store8(PL, acc, bz, w, lane);
    }
    __syncthreads();

    // ---- hidden layers 1..3 ----
    hidden_layer8(PL, (const short8*)P.Bh1 + (size_t)n * 8192,
                      (const short8*)P.Bl1 + (size_t)n * 8192,
                      P.bc1 + n * 256, w, lane, lanep);
    hidden_layer8(PL, (const short8*)P.Bh2 + (size_t)n * 8192,
                      (const short8*)P.Bl2 + (size_t)n * 8192,
                      P.bc2 + n * 256, w, lane, lanep);
    hidden_layer8(PL, (const short8*)P.Bh3 + (size_t)n * 8192,
                      (const short8*)P.Bl3 + (size_t)n * 8192,
                      P.bc3 + n * 256, w, lane, lanep);

    // ---- layer 4: 256 -> 3 via MFMA; waves 0..3 handle p-tile mt=w ----
    if (w < 4) {
        const short8* B4h = (const short8*)P.Bh4 + (n << 9);
        const short8* B4l = (const short8*)P.Bl4 + (n << 9);
        const short8* a0 = (const short8*)&PL[0][lanep * 8];
        const short8* a1 = (const short8*)&PL[1][lanep * 8];
        f32x4 acc4 = (f32x4){0.f, 0.f, 0.f, 0.f};
        #pragma unroll
        for (int kc = 0; kc < 8; ++kc) {
            short8 ah = a0[(kc * 4 + w) << 6];
            short8 al = a1[(kc * 4 + w) << 6];
            short8 bh = B4h[kc * 64 + lane];
            short8 bl = B4l[kc * 64 + lane];
            acc4 = MFMA16(ah, bh, acc4);
            acc4 = MFMA16(ah, bl, acc4);
            acc4 = MFMA16(al, bh, acc4);
        }
        if (col < 3) {
            const float bo = P.bc4[n * 3 + col];
            #pragma unroll
            for (int r = 0; r < 4; ++r) {
                const int p = (w << 4) + (quad << 2) + r;
                P.out[((long)(n * N_PTS + p0g + p)) * 3 + col] = acc4[r] + bo;
            }
        }
    }
}

// ---------------------------------------------------------------------------
extern "C" void kernel_launch(void* const* d_in, const int* in_sizes, int n_in,
                              void* d_out, int out_size, void* d_ws, size_t ws_size,
                              hipStream_t stream) {
    const float* latents = (const float*)d_in[0];
    const float* coords  = (const float*)d_in[1];
    const float* gw[5] = { (const float*)d_in[2], (const float*)d_in[4],
                           (const float*)d_in[6], (const float*)d_in[8],
                           (const float*)d_in[10] };
    const float* gb[5] = { (const float*)d_in[3], (const float*)d_in[5],
                           (const float*)d_in[7], (const float*)d_in[9],
                           (const float*)d_in[11] };
    const float* w[5]  = { (const float*)d_in[12], (const float*)d_in[14],
                           (const float*)d_in[16], (const float*)d_in[18],
                           (const float*)d_in[20] };
    const float* b[5]  = { (const float*)d_in[13], (const float*)d_in[15],
                           (const float*)d_in[17], (const float*)d_in[19],
                           (const float*)d_in[21] };

    char* ws = (char*)d_ws;
    size_t off = 0;
    auto alloc = [&](size_t bytes) { char* p = ws + off; off += (bytes + 255) & ~(size_t)255; return p; };
    int*   idxl = (int*)  alloc(5 * 64 * 256 * 4);
    float* vall = (float*)alloc(5 * 64 * 256 * 4);
    int*   cnt  = (int*)  alloc(5 * 1024 * 4);
    int2*  inv  = (int2*) alloc((size_t)5 * 1024 * 64 * 8);
    float* bc1  = (float*)alloc((size_t)64 * 256 * 4);
    float* bc2  = (float*)alloc((size_t)64 * 256 * 4);
    float* bc3  = (float*)alloc((size_t)64 * 256 * 4);
    float* bc4  = (float*)alloc((size_t)64 * 3 * 4);
    unsigned short* W0F = (unsigned short*)alloc((size_t)64 * 8192 * 2);
    const size_t PLANE = (size_t)64 * 65536 * 2;   // 8 MB per bf16 plane
    unsigned short* Bh1 = (unsigned short*)alloc(PLANE);
    unsigned short* Bl1 = (unsigned short*)alloc(PLANE);
    unsigned short* Bh2 = (unsigned short*)alloc(PLANE);
    unsigned short* Bl2 = (unsigned short*)alloc(PLANE);
    unsigned short* Bh3 = (unsigned short*)alloc(PLANE);
    unsigned short* Bl3 = (unsigned short*)alloc(PLANE);
    unsigned short* Bh4 = (unsigned short*)alloc((size_t)64 * 4096 * 2);
    unsigned short* Bl4 = (unsigned short*)alloc((size_t)64 * 4096 * 2);

    // zero the inverted-list counters
    hipMemsetAsync(cnt, 0, 5 * 1024 * 4, stream);

    // 1) gate + top-k (+ inverted lists)
    GateParams gp;
    gp.latents = latents;
    for (int l = 0; l < 5; ++l) { gp.gw[l] = gw[l]; gp.gb[l] = gb[l]; }
    gp.idx_out = idxl; gp.val_out = vall;
    gp.cnt = cnt; gp.inv = inv;
    gp.E[0]=8; gp.E[1]=16; gp.E[2]=64; gp.E[3]=256; gp.E[4]=1024;
    gp.K[0]=4; gp.K[1]=4;  gp.K[2]=32; gp.K[3]=32;  gp.K[4]=256;
    hipLaunchKernelGGL(gate_topk, dim3(64, 5), dim3(256), 0, stream, gp);

    // 2) combines (W0F + inverted hidden/L4 + biases)
    CombParams cp;
    cp.w0 = w[0]; cp.b0 = b[0]; cp.w1 = w[1]; cp.b1 = b[1];
    cp.w2 = w[2]; cp.b2 = b[2]; cp.w3 = w[3]; cp.b3 = b[3];
    cp.w4 = w[4]; cp.b4 = b[4];
    cp.idxl = idxl; cp.vall = vall;
    cp.cnt = cnt; cp.inv = inv;
    cp.W0F = W0F;
    cp.Bh1 = Bh1; cp.Bl1 = Bl1; cp.Bh2 = Bh2; cp.Bl2 = Bl2;
    cp.Bh3 = Bh3; cp.Bl3 = Bl3; cp.Bh4 = Bh4; cp.Bl4 = Bl4;
    cp.bc1 = bc1; cp.bc2 = bc2; cp.bc3 = bc3; cp.bc4 = bc4;
    hipLaunchKernelGGL(combine_all, dim3(899), dim3(256), 0, stream, cp);

    // 3) fused 5-layer MLP (64 points per block, 8 waves) — exact r4
    FusedParams fp;
    fp.coords = coords;
    fp.W0F = W0F;
    fp.Bh1 = Bh1; fp.Bl1 = Bl1; fp.bc1 = bc1;
    fp.Bh2 = Bh2; fp.Bl2 = Bl2; fp.bc2 = bc2;
    fp.Bh3 = Bh3; fp.Bl3 = Bl3; fp.bc3 = bc3;
    fp.Bh4 = Bh4; fp.Bl4 = Bl4; fp.bc4 = bc4;
    fp.out = (float*)d_out;
    hipLaunchKernelGGL(fused_mlp, dim3(64 * 128), dim3(512), 0, stream, fp);
}